// Round 6
// baseline (103.707 us; speedup 1.0000x reference)
//
#include <hip/hip_runtime.h>
#include <math.h>

#define NQ    14
#define DIM   16384
#define DEPTH 4

// Packed-fp32 complex: f2 = (re, im) -> v_pk_fma_f32.
typedef __attribute__((ext_vector_type(2))) float f2;
typedef __attribute__((ext_vector_type(4))) float f4;

__device__ __forceinline__ f2 cmul(f2 a, f2 b) {
    return (f2){a.x*b.x - a.y*b.y, a.x*b.y + a.y*b.x};
}
// out = u*x + v*y (complex), pre-swapped forms us=(-u.i,u.r): 1 pk_mul + 3 pk_fma
__device__ __forceinline__ f2 cmac2(f2 x, f2 u, f2 us, f2 y, f2 v, f2 vs) {
    f2 r = x.xx * u;
    r += x.yy * us;
    r += y.xx * v;
    r += y.yy * vs;
    return r;
}

// LDS swizzle: bank-pair (b64) = sw(e)&15 = e[3:0]^e[9:6]. Both sweep mappings
// below give exactly 4 lanes per bank pair for every ds_read/write_b64.
__device__ __forceinline__ int sw(int e) { return e ^ ((e >> 6) & 0xF); }

// CZ chain sign: parity of adjacent-bit products.
__device__ __forceinline__ float czsgn(int e) {
    return (__popc(e & (e >> 1)) & 1) ? -1.0f : 1.0f;
}

// ---- cross-lane exchanges (lane-bit butterflies, no LDS state round-trip) ----
template<int CTRL>
__device__ __forceinline__ f2 dpp2(f2 v) {
    union U { f2 f; int i[2]; } u, r;
    u.f = v;
    r.i[0] = __builtin_amdgcn_update_dpp(0, u.i[0], CTRL, 0xF, 0xF, true);
    r.i[1] = __builtin_amdgcn_update_dpp(0, u.i[1], CTRL, 0xF, 0xF, true);
    return r.f;
}
__device__ __forceinline__ f2 swzx4(f2 v) {      // lane ^ 4 via ds_swizzle BitMode
    union U { f2 f; int i[2]; } u, r;
    u.f = v;
    r.i[0] = __builtin_amdgcn_ds_swizzle(u.i[0], 0x101F);
    r.i[1] = __builtin_amdgcn_ds_swizzle(u.i[1], 0x101F);
    return r.f;
}
template<int XB> __device__ __forceinline__ f2 lxchg(f2 v);
template<> __device__ __forceinline__ f2 lxchg<1>(f2 v) { return dpp2<0xB1>(v); }  // quad_perm [1,0,3,2]
template<> __device__ __forceinline__ f2 lxchg<2>(f2 v) { return dpp2<0x4E>(v); }  // quad_perm [2,3,0,1]
template<> __device__ __forceinline__ f2 lxchg<4>(f2 v) { return swzx4(v); }
template<> __device__ __forceinline__ f2 lxchg<8>(f2 v) { return dpp2<0x128>(v); } // row_ror:8 == xor 8

// ---- element mappings (thread t[9:0], group s, register amp l[2:0]) ----
// SWEEP 0 covers qubits 0-6:  e[13:11]=l (q0,q1,q2), e[10:7]=t[3:0] (q3..q6 lane
//   butterflies xor8/4/2/1), e6=t6 e5=t7 e4=t8 e3=t5 e2=t9 e1=s e0=t4.
//   bankpair = (t5^t2, t9^t1, s^t0, t4^t6): 16 values x 4 lanes. ✓
// SWEEP 1 covers qubits 7-13: e13=s, e[12:7]=t[9:4], e[6:4]=l (q7,q8,q9),
//   e[3:0]=t[3:0] (q10..q13). bankpair = (t3^t6, t2^t5, t1^t4, t0^l2): 4 lanes. ✓
template<int SWEEP>
__device__ __forceinline__ int emapS(int t, int s, int l) {
    if (SWEEP == 0)
        return (l << 11) | ((t & 15) << 7)
             | (((t >> 6) & 1) << 6) | (((t >> 7) & 1) << 5) | (((t >> 8) & 1) << 4)
             | (((t >> 5) & 1) << 3) | (((t >> 9) & 1) << 2) | (s << 1) | ((t >> 4) & 1);
    return (s << 13) | (((t >> 4) & 63) << 7) | (l << 4) | (t & 15);
}

// Register-qubit gate: butterfly across amp-index bit MASK.
template<int MASK>
__device__ __forceinline__ void reg_gate(f2 a[8], const f4* G) {
    f4 g0 = G[0], g1 = G[1], g2 = G[2], g3 = G[3];
    #pragma unroll
    for (int l = 0; l < 8; ++l) {
        if (l & MASK) continue;
        const int j = l | MASK;
        f2 x = a[l], y = a[j];
        a[l] = cmac2(x, g0.xy, g0.zw, y, g1.xy, g1.zw);
        a[j] = cmac2(x, g2.xy, g2.zw, y, g3.xy, g3.zw);
    }
}

// Lane-qubit gate: exchange partner amp cross-lane; each lane computes only its
// own half. new_own = c1*own + c2*partner; lo lane: (u00,u01), hi: (u11,u10) —
// selected via per-lane LDS address (2 addrs/wave, cheap).
template<int XB>
__device__ __forceinline__ void lane_gate(f2 a[8], const f4* G, int t) {
    const bool hi = (t & XB) != 0;
    f4 c1 = G[hi ? 3 : 0];
    f4 c2 = G[hi ? 2 : 1];
    #pragma unroll
    for (int l = 0; l < 8; ++l) {
        f2 p = lxchg<XB>(a[l]);
        a[l] = cmac2(a[l], c1.xy, c1.zw, p, c2.xy, c2.zw);
    }
}

template<int SWEEP>
__device__ __forceinline__ void do_sweep(f2* st, const f4 (*gl)[4], int t,
                                         bool mulsign)
{
    constexpr int QB = (SWEEP == 0) ? 0 : 7;
    #pragma unroll 1   // groups sequential: 8 amps live (64-VGPR budget)
    for (int s = 0; s < 2; ++s) {
        f2 a[8];
        #pragma unroll
        for (int l = 0; l < 8; ++l) a[l] = st[sw(emapS<SWEEP>(t, s, l))];
        if (mulsign) {  // CZ of the previous layer, fused into the load
            #pragma unroll
            for (int l = 0; l < 8; ++l) a[l] *= czsgn(emapS<SWEEP>(t, s, l));
        }
        reg_gate<4>(a, gl[QB + 0]);
        reg_gate<2>(a, gl[QB + 1]);
        reg_gate<1>(a, gl[QB + 2]);
        lane_gate<8>(a, gl[QB + 3], t);
        lane_gate<4>(a, gl[QB + 4], t);
        lane_gate<2>(a, gl[QB + 5], t);
        lane_gate<1>(a, gl[QB + 6], t);
        #pragma unroll
        for (int l = 0; l < 8; ++l) st[sw(emapS<SWEEP>(t, s, l))] = a[l];
    }
}

// Final sweep (layer 3, qubits 7-13) + fused probability reduction.
// e = (s<<13)|(t[9:4]<<7)|(l<<4)|t[3:0]: sign bits are s (wire 0), t[9:4]
// (wires 1-6, thread-uniform), l (wires 7-9), t[3:0] (wires 10-13) -> only
// 5 accumulators, no acc[14] spill.
__device__ __forceinline__ void do_sweep_final(f2* st, const f4 (*gl)[4], int t,
        float& SU, float& A0, float& Q7, float& Q8, float& Q9)
{
    SU = A0 = Q7 = Q8 = Q9 = 0.f;
    #pragma unroll 1
    for (int s = 0; s < 2; ++s) {
        f2 a[8];
        #pragma unroll
        for (int l = 0; l < 8; ++l) a[l] = st[sw(emapS<1>(t, s, l))];
        reg_gate<4>(a, gl[7]);
        reg_gate<2>(a, gl[8]);
        reg_gate<1>(a, gl[9]);
        lane_gate<8>(a, gl[10], t);
        lane_gate<4>(a, gl[11], t);
        lane_gate<2>(a, gl[12], t);
        lane_gate<1>(a, gl[13], t);
        float p0 = a[0].x*a[0].x + a[0].y*a[0].y;
        float p1 = a[1].x*a[1].x + a[1].y*a[1].y;
        float p2 = a[2].x*a[2].x + a[2].y*a[2].y;
        float p3 = a[3].x*a[3].x + a[3].y*a[3].y;
        float p4 = a[4].x*a[4].x + a[4].y*a[4].y;
        float p5 = a[5].x*a[5].x + a[5].y*a[5].y;
        float p6 = a[6].x*a[6].x + a[6].y*a[6].y;
        float p7 = a[7].x*a[7].x + a[7].y*a[7].y;
        float e0 = p0 + p1, e1 = p2 + p3, e2 = p4 + p5, e3 = p6 + p7;
        float G = (e0 + e1) + (e2 + e3);
        SU += G;
        A0 += s ? -G : G;                      // wire 0: e13 = s
        Q7 += (e0 + e1) - (e2 + e3);           // wire 7: e6 = l2
        Q8 += (e0 - e1) + (e2 - e3);           // wire 8: e5 = l1
        Q9 += (p0 - p1) + (p2 - p3) + (p4 - p5) + (p6 - p7);  // wire 9: e4 = l0
    }
}

__global__ __launch_bounds__(1024)
void qlg_kernel(const float* __restrict__ cond,
                const float* __restrict__ Wenc,
                const float* __restrict__ benc,
                const float* __restrict__ wts,
                float* __restrict__ out)
{
    __shared__ f2 st[DIM];                  // 128 KB state (swizzled index)
    __shared__ f4 gates[DEPTH][NQ][4];      // per gate row: (u | u_swapped)
    __shared__ f2 qv[NQ][2];
    __shared__ f2 Phi[128];
    __shared__ f2 Plo[128];
    __shared__ float embS[NQ];
    __shared__ float wred[16][NQ];
    __shared__ float lat[NQ];

    const int b = blockIdx.x;
    const int t = threadIdx.x;

    // ---- stage 1: embedding (SiLU) + gate matrices ----
    if (t < NQ) {
        float s = benc[t];
        #pragma unroll
        for (int k = 0; k < NQ; ++k) s += cond[b*NQ + k] * Wenc[t*NQ + k];
        embS[t] = s / (1.0f + __expf(-s));
    }
    if (t >= 64 && t < 64 + DEPTH*NQ) {
        const int gi = t - 64;
        const int d = gi / NQ, w = gi % NQ;
        const float p0 = wts[(d*NQ + w)*3 + 0];
        const float p1 = wts[(d*NQ + w)*3 + 1];
        const float p2 = wts[(d*NQ + w)*3 + 2];
        float s0, c0, s1, c1, s2, c2;
        sincosf(0.5f*p0, &s0, &c0);
        sincosf(0.5f*p1, &s1, &c1);
        sincosf(0.5f*p2, &s2, &c2);
        // U = RY(p2) * RX(p1) * RZ(p0)
        f2 e0  = (f2){c0, -s0};
        f2 e0c = (f2){c0,  s0};
        f2 is1 = (f2){0.f, -s1};
        f2 m00 = c1 * e0;
        f2 m01 = cmul(is1, e0c);
        f2 m10 = cmul(is1, e0);
        f2 m11 = c1 * e0c;
        f2 u00 = c2*m00 - s2*m10;
        f2 u01 = c2*m01 - s2*m11;
        f2 u10 = s2*m00 + c2*m10;
        f2 u11 = s2*m01 + c2*m11;
        gates[d][w][0] = (f4){u00.x, u00.y, -u00.y, u00.x};
        gates[d][w][1] = (f4){u01.x, u01.y, -u01.y, u01.x};
        gates[d][w][2] = (f4){u10.x, u10.y, -u10.y, u10.x};
        gates[d][w][3] = (f4){u11.x, u11.y, -u11.y, u11.x};
    }
    __syncthreads();

    // ---- stage 2: per-wire 2-vectors after encoding + layer 0 ----
    if (t < NQ) {
        float v = embS[t];
        float s, c;
        sincosf(0.5f*v, &s, &c);
        f2 a0 = (f2){c*c,  s*s};
        f2 a1 = (f2){s*c, -s*c};
        f2 u00 = gates[0][t][0].xy, u01 = gates[0][t][1].xy;
        f2 u10 = gates[0][t][2].xy, u11 = gates[0][t][3].xy;
        qv[t][0] = cmul(u00, a0) + cmul(u01, a1);
        qv[t][1] = cmul(u10, a0) + cmul(u11, a1);
    }
    __syncthreads();

    // ---- stage 3: partial-product tables ----
    if (t < 128) {
        f2 p = qv[0][(t >> 6) & 1];
        #pragma unroll
        for (int w = 1; w <= 6; ++w) p = cmul(p, qv[w][(t >> (6 - w)) & 1]);
        Phi[t] = p;
    } else if (t < 256) {
        const int j = t - 128;
        f2 p = qv[7][(j >> 6) & 1];
        #pragma unroll
        for (int w = 8; w <= 13; ++w) p = cmul(p, qv[w][(j >> (13 - w)) & 1]);
        Plo[j] = p;
    }
    __syncthreads();

    // ---- stage 4: build product state, fusing CZ after layer 0 ----
    #pragma unroll
    for (int l = 0; l < 16; ++l) {
        const int e = (l << 10) | t;
        f2 v = cmul(Phi[e >> 7], Plo[e & 127]);
        st[sw(e)] = v * czsgn(e);
    }
    __syncthreads();

    // ---- stage 5: layers 1..3, 2 sweeps each (7 qubits per sweep) ----
    do_sweep<0>(st, gates[1], t, false); __syncthreads();  // CZ(L0) fused in build
    do_sweep<1>(st, gates[1], t, false); __syncthreads();
    do_sweep<0>(st, gates[2], t, true);  __syncthreads();  // CZ after layer 1
    do_sweep<1>(st, gates[2], t, false); __syncthreads();
    do_sweep<0>(st, gates[3], t, true);  __syncthreads();  // CZ after layer 2
    float SU, A0, Q7, Q8, Q9;
    do_sweep_final(st, gates[3], t, SU, A0, Q7, Q8, Q9);
    // (CZ after layer 3 dropped: |psi|^2 invariant)

    // ---- stage 6: reduce to 14 expectations, layernorm ----
    {
        const int lane = t & 63, wv = t >> 6;
        #pragma unroll
        for (int w = 0; w < NQ; ++w) {
            float v;
            if      (w == 0) v = A0;
            else if (w == 7) v = Q7;
            else if (w == 8) v = Q8;
            else if (w == 9) v = Q9;
            else if (w <= 6) v = ((t >> (10 - w)) & 1) ? -SU : SU;   // e bits 12..7
            else             v = ((t >> (13 - w)) & 1) ? -SU : SU;   // e bits 3..0
            #pragma unroll
            for (int off = 32; off > 0; off >>= 1) v += __shfl_down(v, off, 64);
            if (lane == 0) wred[wv][w] = v;
        }
    }
    __syncthreads();
    if (t < NQ) {
        float s = 0.f;
        #pragma unroll
        for (int k = 0; k < 16; ++k) s += wred[k][t];
        lat[t] = s;
    }
    __syncthreads();
    if (t < NQ) {
        float mu = 0.f;
        #pragma unroll
        for (int k = 0; k < NQ; ++k) mu += lat[k];
        mu *= (1.0f / NQ);
        float var = 0.f;
        #pragma unroll
        for (int k = 0; k < NQ; ++k) { float dv = lat[k] - mu; var += dv*dv; }
        var *= (1.0f / NQ);
        out[b*NQ + t] = (lat[t] - mu) * rsqrtf(var + 1e-5f);
    }
}

extern "C" void kernel_launch(void* const* d_in, const int* in_sizes, int n_in,
                              void* d_out, int out_size, void* d_ws, size_t ws_size,
                              hipStream_t stream)
{
    (void)n_in; (void)d_ws; (void)ws_size; (void)out_size;
    const float* cond = (const float*)d_in[0];
    const float* Wenc = (const float*)d_in[1];
    const float* benc = (const float*)d_in[2];
    const float* wts  = (const float*)d_in[3];
    float* out = (float*)d_out;
    const int B = in_sizes[0] / NQ;   // 256
    qlg_kernel<<<dim3(B), dim3(1024), 0, stream>>>(cond, Wenc, benc, wts, out);
}

// Round 7
// 98.463 us; speedup vs baseline: 1.0533x; 1.0533x over previous
//
#include <hip/hip_runtime.h>
#include <math.h>

#define NQ    14
#define DIM   16384
#define DEPTH 4

// Packed-fp32 complex: f2 = (re, im) -> v_pk_fma_f32.
typedef __attribute__((ext_vector_type(2))) float f2;
typedef __attribute__((ext_vector_type(4))) float f4;

__device__ __forceinline__ f2 cmul(f2 a, f2 b) {
    return (f2){a.x*b.x - a.y*b.y, a.x*b.y + a.y*b.x};
}
// out = u*x + v*y (complex), pre-swapped forms us=(-u.i,u.r): 1 pk_mul + 3 pk_fma
__device__ __forceinline__ f2 cmac2(f2 x, f2 u, f2 us, f2 y, f2 v, f2 vs) {
    f2 r = x.xx * u;
    r += x.yy * us;
    r += y.xx * v;
    r += y.yy * vs;
    return r;
}

// CZ chain sign (generic, used in build only): parity of adjacent-bit products.
__device__ __forceinline__ float czsgn(int e) {
    return (__popc(e & (e >> 1)) & 1) ? -1.0f : 1.0f;
}

// ---------------- LDS layout ----------------
// Bit-permutation layout m(e): m[3:0]=e[9:6], m[9:4]=e[5:0], m[13:10]=e[13:10].
// In BOTH sweeps (and build) m[3:0] are lane-varying thread bits -> every
// ds_read/write_b64 spreads 64 lanes over 16 bank pairs x 4 lanes (optimal),
// AND amp addresses are base(t) + compile-const*l (no per-amp address math).
//
// Sweep A covers q0-7:  e = (l<<10) | ((t&15)<<6) | (t>>4)
//   q0-3 = e[13:10] = l (register butterflies), q4-7 = e[9:6] = t[3:0] (lane
//   butterflies xor8/4/2/1).  m = t + (l<<10).
// Sweep B covers q8-13: e = ((t>>2)<<6) | (l<<2) | (t&3)
//   q8-11 = e[5:2] = l, q12-13 = e[1:0] = t[1:0] (lane xor2/xor1).
//   m = ((t>>2)&15) | ((t&3)<<4) | (l<<6) | ((t>>6)<<10).

// ---- cross-lane exchanges ----
template<int CTRL>
__device__ __forceinline__ f2 dpp2(f2 v) {
    union U { f2 f; int i[2]; } u, r;
    u.f = v;
    r.i[0] = __builtin_amdgcn_update_dpp(0, u.i[0], CTRL, 0xF, 0xF, true);
    r.i[1] = __builtin_amdgcn_update_dpp(0, u.i[1], CTRL, 0xF, 0xF, true);
    return r.f;
}
__device__ __forceinline__ f2 swzx4(f2 v) {      // lane ^ 4 via ds_swizzle BitMode
    union U { f2 f; int i[2]; } u, r;
    u.f = v;
    r.i[0] = __builtin_amdgcn_ds_swizzle(u.i[0], 0x101F);
    r.i[1] = __builtin_amdgcn_ds_swizzle(u.i[1], 0x101F);
    return r.f;
}
template<int XB> __device__ __forceinline__ f2 lxchg(f2 v);
template<> __device__ __forceinline__ f2 lxchg<1>(f2 v) { return dpp2<0xB1>(v); }  // quad_perm [1,0,3,2]
template<> __device__ __forceinline__ f2 lxchg<2>(f2 v) { return dpp2<0x4E>(v); }  // quad_perm [2,3,0,1]
template<> __device__ __forceinline__ f2 lxchg<4>(f2 v) { return swzx4(v); }
template<> __device__ __forceinline__ f2 lxchg<8>(f2 v) { return dpp2<0x128>(v); } // row_ror:8 == xor 8

// Register-qubit gate over 16 amps: butterfly across amp-index bit MASK.
template<int MASK>
__device__ __forceinline__ void reg_gate(f2 a[16], const f4* G) {
    f4 g0 = G[0], g1 = G[1], g2 = G[2], g3 = G[3];
    #pragma unroll
    for (int l = 0; l < 16; ++l) {
        if (l & MASK) continue;
        const int j = l | MASK;
        f2 x = a[l], y = a[j];
        a[l] = cmac2(x, g0.xy, g0.zw, y, g1.xy, g1.zw);
        a[j] = cmac2(x, g2.xy, g2.zw, y, g3.xy, g3.zw);
    }
}

// Lane-qubit gate: exchange partner cross-lane; lane computes its own half.
// lo lane: (u00,u01) = rows 0,1; hi lane: (u11,u10) = rows 3,2.
template<int XB>
__device__ __forceinline__ void lane_gate(f2 a[16], const f4* G, int t) {
    const bool hi = (t & XB) != 0;
    f4 c1 = G[hi ? 3 : 0];
    f4 c2 = G[hi ? 2 : 1];
    #pragma unroll
    for (int l = 0; l < 16; ++l) {
        f2 p = lxchg<XB>(a[l]);
        a[l] = cmac2(a[l], c1.xy, c1.zw, p, c2.xy, c2.zw);
    }
}

// Sweep A: qubits 0-7.  MULSIGN fuses the previous layer's CZ into the load,
// via decomposition sign(e) = (-1)^{pT} * (-1)^{pl(l)} * (-1)^{l0 & t3}:
// e-pairs inside the t-part give pT (runtime, once), pairs inside l give a
// compile-time constant per l, and the single boundary pair (e10,e9)=(l0,t3)
// gives the cross term. 1 pk_mul per amp, no per-amp popc.
template<bool MULSIGN>
__device__ __forceinline__ void sweepA(f2* st, const f4 (*gl)[4], int t)
{
    f2 a[16];
    #pragma unroll
    for (int l = 0; l < 16; ++l) a[l] = st[t + (l << 10)];
    if (MULSIGN) {
        const int T = ((t & 15) << 6) | (t >> 4);
        const int pT = __popc(T & (T >> 1)) & 1;
        const float F0 = pT ? -1.f : 1.f;
        const float F1 = (pT ^ ((t >> 3) & 1)) ? -1.f : 1.f;
        #pragma unroll
        for (int l = 0; l < 16; ++l) {
            float s = (l & 1) ? F1 : F0;
            if (__popc(l & (l >> 1)) & 1) s = -s;   // compile-time fold
            a[l] *= s;
        }
    }
    reg_gate<8>(a, gl[0]);      // q0 <-> e13 = l[3]
    reg_gate<4>(a, gl[1]);      // q1 <-> e12 = l[2]
    reg_gate<2>(a, gl[2]);      // q2 <-> e11 = l[1]
    reg_gate<1>(a, gl[3]);      // q3 <-> e10 = l[0]
    lane_gate<8>(a, gl[4], t);  // q4 <-> e9 = t[3]
    lane_gate<4>(a, gl[5], t);  // q5 <-> e8 = t[2]
    lane_gate<2>(a, gl[6], t);  // q6 <-> e7 = t[1]
    lane_gate<1>(a, gl[7], t);  // q7 <-> e6 = t[0]
    #pragma unroll
    for (int l = 0; l < 16; ++l) st[t + (l << 10)] = a[l];
}

__device__ __forceinline__ int baseB(int t) {
    return ((t >> 2) & 15) | ((t & 3) << 4) | ((t >> 6) << 10);
}

// Sweep B: qubits 8-13.
__device__ __forceinline__ void sweepB(f2* st, const f4 (*gl)[4], int t)
{
    const int mb = baseB(t);
    f2 a[16];
    #pragma unroll
    for (int l = 0; l < 16; ++l) a[l] = st[mb + (l << 6)];
    reg_gate<8>(a, gl[8]);      // q8  <-> e5 = l[3]
    reg_gate<4>(a, gl[9]);      // q9  <-> e4 = l[2]
    reg_gate<2>(a, gl[10]);     // q10 <-> e3 = l[1]
    reg_gate<1>(a, gl[11]);     // q11 <-> e2 = l[0]
    lane_gate<2>(a, gl[12], t); // q12 <-> e1 = t[1]
    lane_gate<1>(a, gl[13], t); // q13 <-> e0 = t[0]
    #pragma unroll
    for (int l = 0; l < 16; ++l) st[mb + (l << 6)] = a[l];
}

// Final sweep B (layer 3) + fused probability reduction. Sign bits of wire w
// live at e[13-w]: wires 0-7 -> t[9:2] and 12,13 -> t[1:0] (thread-uniform,
// folded onto SU at reduce time); wires 8-11 -> l[3:0] (4 accumulators).
__device__ __forceinline__ void sweepB_final(f2* st, const f4 (*gl)[4], int t,
        float& SU, float& Q8, float& Q9, float& Q10, float& Q11)
{
    const int mb = baseB(t);
    f2 a[16];
    #pragma unroll
    for (int l = 0; l < 16; ++l) a[l] = st[mb + (l << 6)];
    reg_gate<8>(a, gl[8]);
    reg_gate<4>(a, gl[9]);
    reg_gate<2>(a, gl[10]);
    reg_gate<1>(a, gl[11]);
    lane_gate<2>(a, gl[12], t);
    lane_gate<1>(a, gl[13], t);
    SU = Q8 = Q9 = Q10 = Q11 = 0.f;
    #pragma unroll
    for (int l = 0; l < 16; ++l) {
        float p = a[l].x*a[l].x + a[l].y*a[l].y;
        SU  += p;
        Q8  += (l & 8) ? -p : p;
        Q9  += (l & 4) ? -p : p;
        Q10 += (l & 2) ? -p : p;
        Q11 += (l & 1) ? -p : p;
    }
}

__global__ __launch_bounds__(1024)
void qlg_kernel(const float* __restrict__ cond,
                const float* __restrict__ Wenc,
                const float* __restrict__ benc,
                const float* __restrict__ wts,
                float* __restrict__ out)
{
    __shared__ f2 st[DIM];                  // 128 KB state (m-layout)
    __shared__ f4 gates[DEPTH][NQ][4];      // per gate row: (u | u_swapped)
    __shared__ f2 qv[NQ][2];
    __shared__ f2 Phi[128];
    __shared__ f2 Plo[128];
    __shared__ float embS[NQ];
    __shared__ float wred[16][NQ];
    __shared__ float lat[NQ];

    const int b = blockIdx.x;
    const int t = threadIdx.x;

    // ---- stage 1: embedding (SiLU) + gate matrices ----
    if (t < NQ) {
        float s = benc[t];
        #pragma unroll
        for (int k = 0; k < NQ; ++k) s += cond[b*NQ + k] * Wenc[t*NQ + k];
        embS[t] = s / (1.0f + __expf(-s));
    }
    if (t >= 64 && t < 64 + DEPTH*NQ) {
        const int gi = t - 64;
        const int d = gi / NQ, w = gi % NQ;
        const float p0 = wts[(d*NQ + w)*3 + 0];
        const float p1 = wts[(d*NQ + w)*3 + 1];
        const float p2 = wts[(d*NQ + w)*3 + 2];
        float s0, c0, s1, c1, s2, c2;
        sincosf(0.5f*p0, &s0, &c0);
        sincosf(0.5f*p1, &s1, &c1);
        sincosf(0.5f*p2, &s2, &c2);
        // U = RY(p2) * RX(p1) * RZ(p0)
        f2 e0  = (f2){c0, -s0};
        f2 e0c = (f2){c0,  s0};
        f2 is1 = (f2){0.f, -s1};
        f2 m00 = c1 * e0;
        f2 m01 = cmul(is1, e0c);
        f2 m10 = cmul(is1, e0);
        f2 m11 = c1 * e0c;
        f2 u00 = c2*m00 - s2*m10;
        f2 u01 = c2*m01 - s2*m11;
        f2 u10 = s2*m00 + c2*m10;
        f2 u11 = s2*m01 + c2*m11;
        gates[d][w][0] = (f4){u00.x, u00.y, -u00.y, u00.x};
        gates[d][w][1] = (f4){u01.x, u01.y, -u01.y, u01.x};
        gates[d][w][2] = (f4){u10.x, u10.y, -u10.y, u10.x};
        gates[d][w][3] = (f4){u11.x, u11.y, -u11.y, u11.x};
    }
    __syncthreads();

    // ---- stage 2: per-wire 2-vectors after encoding + layer 0 ----
    if (t < NQ) {
        float v = embS[t];
        float s, c;
        sincosf(0.5f*v, &s, &c);
        f2 a0 = (f2){c*c,  s*s};
        f2 a1 = (f2){s*c, -s*c};
        f2 u00 = gates[0][t][0].xy, u01 = gates[0][t][1].xy;
        f2 u10 = gates[0][t][2].xy, u11 = gates[0][t][3].xy;
        qv[t][0] = cmul(u00, a0) + cmul(u01, a1);
        qv[t][1] = cmul(u10, a0) + cmul(u11, a1);
    }
    __syncthreads();

    // ---- stage 3: partial-product tables ----
    if (t < 128) {
        f2 p = qv[0][(t >> 6) & 1];
        #pragma unroll
        for (int w = 1; w <= 6; ++w) p = cmul(p, qv[w][(t >> (6 - w)) & 1]);
        Phi[t] = p;
    } else if (t < 256) {
        const int j = t - 128;
        f2 p = qv[7][(j >> 6) & 1];
        #pragma unroll
        for (int w = 8; w <= 13; ++w) p = cmul(p, qv[w][(j >> (13 - w)) & 1]);
        Plo[j] = p;
    }
    __syncthreads();

    // ---- stage 4: build product state (sweep-A e-assignment -> m = t+(l<<10)),
    //      fusing CZ after layer 0 ----
    #pragma unroll
    for (int l = 0; l < 16; ++l) {
        const int e = (l << 10) | ((t & 15) << 6) | (t >> 4);
        f2 v = cmul(Phi[e >> 7], Plo[e & 127]);
        st[t + (l << 10)] = v * czsgn(e);
    }
    __syncthreads();

    // ---- stage 5: layers 1..3, 2 sweeps each ----
    sweepA<false>(st, gates[1], t); __syncthreads();  // CZ(L0) fused in build
    sweepB(st, gates[1], t);        __syncthreads();
    sweepA<true>(st, gates[2], t);  __syncthreads();  // CZ after layer 1
    sweepB(st, gates[2], t);        __syncthreads();
    sweepA<true>(st, gates[3], t);  __syncthreads();  // CZ after layer 2
    float SU, Q8, Q9, Q10, Q11;
    sweepB_final(st, gates[3], t, SU, Q8, Q9, Q10, Q11);
    // (CZ after layer 3 dropped: |psi|^2 invariant)

    // ---- stage 6: reduce to 14 expectations, layernorm ----
    {
        const int lane = t & 63, wv = t >> 6;
        #pragma unroll
        for (int w = 0; w < NQ; ++w) {
            float v;
            if      (w == 8)  v = Q8;
            else if (w == 9)  v = Q9;
            else if (w == 10) v = Q10;
            else if (w == 11) v = Q11;
            else if (w <= 7)  v = ((t >> (9 - w)) & 1) ? -SU : SU;   // e13..e6
            else              v = ((t >> (13 - w)) & 1) ? -SU : SU;  // e1, e0
            #pragma unroll
            for (int off = 32; off > 0; off >>= 1) v += __shfl_down(v, off, 64);
            if (lane == 0) wred[wv][w] = v;
        }
    }
    __syncthreads();
    if (t < NQ) {
        float s = 0.f;
        #pragma unroll
        for (int k = 0; k < 16; ++k) s += wred[k][t];
        lat[t] = s;
    }
    __syncthreads();
    if (t < NQ) {
        float mu = 0.f;
        #pragma unroll
        for (int k = 0; k < NQ; ++k) mu += lat[k];
        mu *= (1.0f / NQ);
        float var = 0.f;
        #pragma unroll
        for (int k = 0; k < NQ; ++k) { float dv = lat[k] - mu; var += dv*dv; }
        var *= (1.0f / NQ);
        out[b*NQ + t] = (lat[t] - mu) * rsqrtf(var + 1e-5f);
    }
}

extern "C" void kernel_launch(void* const* d_in, const int* in_sizes, int n_in,
                              void* d_out, int out_size, void* d_ws, size_t ws_size,
                              hipStream_t stream)
{
    (void)n_in; (void)d_ws; (void)ws_size; (void)out_size;
    const float* cond = (const float*)d_in[0];
    const float* Wenc = (const float*)d_in[1];
    const float* benc = (const float*)d_in[2];
    const float* wts  = (const float*)d_in[3];
    float* out = (float*)d_out;
    const int B = in_sizes[0] / NQ;   // 256
    qlg_kernel<<<dim3(B), dim3(1024), 0, stream>>>(cond, Wenc, benc, wts, out);
}

// Round 9
// 95.806 us; speedup vs baseline: 1.0825x; 1.0277x over previous
//
#include <hip/hip_runtime.h>
#include <math.h>

#define NQ    14
#define DIM   16384
#define DEPTH 4

// Packed-fp32 complex: f2 = (re, im) -> v_pk_fma_f32.
typedef __attribute__((ext_vector_type(2))) float f2;
typedef __attribute__((ext_vector_type(4))) float f4;

__device__ __forceinline__ f2 cmul(f2 a, f2 b) {
    return (f2){a.x*b.x - a.y*b.y, a.x*b.y + a.y*b.x};
}
// out = u*x + v*y (complex), pre-swapped forms us=(-u.i,u.r): 1 pk_mul + 3 pk_fma
__device__ __forceinline__ f2 cmac2(f2 x, f2 u, f2 us, f2 y, f2 v, f2 vs) {
    f2 r = x.xx * u;
    r += x.yy * us;
    r += y.xx * v;
    r += y.yy * vs;
    return r;
}

// ---------------- register-resident state ----------------
// 1024 threads x 16 amps = the full 16384-amp state in registers.
// M0 view: e = (l<<10) | (n<<4) | w   (n = t&63 lane, w = t>>6 wave)
//   q0-3 <-> l[3:0] (reg masks 8,4,2,1); q4-9 <-> n[5:0] (lane xor 32..1);
//   q10-13 <-> w (wave bits, need remap).
// M1 view: e = (w<<10) | (n<<4) | l
//   q10-13 <-> l[3:0]; q4-9 <-> n; q0-3 <-> w.
// Remap M0<->M1 through LDS with layout
//   L(e) = e[7:4] | (e[9:8]<<4) | (e[3:0]<<6) | (e[13:10]<<10)
// M0 side address: L = t + (l<<10)            (bank pair = n&15, 16x4 lanes)
// M1 side address: L = n | (w<<10) + (l<<6)   (bank pair = n&15, 16x4 lanes)
// Both sides are base + compile-const*l -> pure imm offsets, zero addr VALU.

// ---- cross-lane exchanges ----
template<int CTRL>
__device__ __forceinline__ f2 dpp2(f2 v) {
    union U { f2 f; int i[2]; } u, r;
    u.f = v;
    r.i[0] = __builtin_amdgcn_update_dpp(0, u.i[0], CTRL, 0xF, 0xF, true);
    r.i[1] = __builtin_amdgcn_update_dpp(0, u.i[1], CTRL, 0xF, 0xF, true);
    return r.f;
}
template<int PAT>
__device__ __forceinline__ f2 swz2(f2 v) {
    union U { f2 f; int i[2]; } u, r;
    u.f = v;
    r.i[0] = __builtin_amdgcn_ds_swizzle(u.i[0], PAT);
    r.i[1] = __builtin_amdgcn_ds_swizzle(u.i[1], PAT);
    return r.f;
}
template<int XB> __device__ __forceinline__ f2 lxchg(f2 v);
template<> __device__ __forceinline__ f2 lxchg<1>(f2 v)  { return dpp2<0xB1>(v); }   // quad_perm [1,0,3,2]
template<> __device__ __forceinline__ f2 lxchg<2>(f2 v)  { return dpp2<0x4E>(v); }   // quad_perm [2,3,0,1]
template<> __device__ __forceinline__ f2 lxchg<4>(f2 v)  { return swz2<0x101F>(v); } // BitMode xor4
template<> __device__ __forceinline__ f2 lxchg<8>(f2 v)  { return dpp2<0x128>(v); }  // row_ror:8 == xor8
template<> __device__ __forceinline__ f2 lxchg<16>(f2 v) { return swz2<0x401F>(v); } // BitMode xor16
template<> __device__ __forceinline__ f2 lxchg<32>(f2 v) {                            // xor32 via shfl
    union U { f2 f; float s[2]; } u, r;
    u.f = v;
    r.s[0] = __shfl_xor(u.s[0], 32, 64);
    r.s[1] = __shfl_xor(u.s[1], 32, 64);
    return r.f;
}

// Register-qubit gate over 16 amps: butterfly across amp-index bit MASK.
template<int MASK>
__device__ __forceinline__ void reg_gate(f2 a[16], const f4* G) {
    f4 g0 = G[0], g1 = G[1], g2 = G[2], g3 = G[3];
    #pragma unroll
    for (int l = 0; l < 16; ++l) {
        if (l & MASK) continue;
        const int j = l | MASK;
        f2 x = a[l], y = a[j];
        a[l] = cmac2(x, g0.xy, g0.zw, y, g1.xy, g1.zw);
        a[j] = cmac2(x, g2.xy, g2.zw, y, g3.xy, g3.zw);
    }
}

// Lane-qubit gate: exchange partner cross-lane; lane computes its own half.
// lo lane: rows 0,1 = (u00,u01); hi lane: rows 3,2 = (u11,u10).
template<int XB>
__device__ __forceinline__ void lane_gate(f2 a[16], const f4* G, int t) {
    const bool hi = (t & XB) != 0;
    f4 c1 = G[hi ? 3 : 0];
    f4 c2 = G[hi ? 2 : 1];
    #pragma unroll
    for (int l = 0; l < 16; ++l) {
        f2 p = lxchg<XB>(a[l]);
        a[l] = cmac2(a[l], c1.xy, c1.zw, p, c2.xy, c2.zw);
    }
}

// CZ sign in M0 view: e = (l<<10)|(n<<4)|w.
// parity = [pairs in w] ^ (n0&w3) ^ [pairs in n] ^ (l0&n5) ^ [pairs in l].
__device__ __forceinline__ void cz_M0(f2 a[16], int t) {
    const int n = t & 63, w = t >> 6;
    const int pT = (__popc(w & (w >> 1)) + __popc(n & (n >> 1)) + ((n & 1) & (w >> 3))) & 1;
    const float F0 = pT ? -1.f : 1.f;
    const float F1 = (pT ^ ((n >> 5) & 1)) ? -1.f : 1.f;
    #pragma unroll
    for (int l = 0; l < 16; ++l) {
        float s = (l & 1) ? F1 : F0;                 // cross term l0 & n5
        if (__popc(l & (l >> 1)) & 1) s = -s;        // compile-time per l
        a[l] *= s;
    }
}

// CZ sign in M1 view: e = (w<<10)|(n<<4)|l.
// parity = [pairs in w] ^ (w0&n5) ^ [pairs in n] ^ (n0&l3) ^ [pairs in l].
__device__ __forceinline__ void cz_M1(f2 a[16], int t) {
    const int n = t & 63, w = t >> 6;
    const int pT = (__popc(w & (w >> 1)) + __popc(n & (n >> 1)) + ((w & 1) & (n >> 5))) & 1;
    const float F0 = pT ? -1.f : 1.f;
    const float F1 = (pT ^ (n & 1)) ? -1.f : 1.f;
    #pragma unroll
    for (int l = 0; l < 16; ++l) {
        float s = (l & 8) ? F1 : F0;                 // cross term l3 & n0
        if (__popc(l & (l >> 1)) & 1) s = -s;        // compile-time per l
        a[l] *= s;
    }
}

__global__ __launch_bounds__(1024)
void qlg_kernel(const float* __restrict__ cond,
                const float* __restrict__ Wenc,
                const float* __restrict__ benc,
                const float* __restrict__ wts,
                float* __restrict__ out)
{
    __shared__ f2 st[DIM];                  // 128 KB remap buffer (L-layout)
    __shared__ f4 gates[DEPTH][NQ][4];      // per gate row: (u | u_swapped)
    __shared__ f2 qv[NQ][2];
    __shared__ f2 Phi[128];
    __shared__ f2 Plo[128];
    __shared__ float embS[NQ];
    __shared__ float wred[16][NQ];
    __shared__ float lat[NQ];

    const int b = blockIdx.x;
    const int t = threadIdx.x;
    const int n = t & 63, w = t >> 6;
    const int bM1 = n | (w << 10);          // M1-side remap base

    // ---- stage 1: embedding (SiLU) + gate matrices ----
    if (t < NQ) {
        float s = benc[t];
        #pragma unroll
        for (int k = 0; k < NQ; ++k) s += cond[b*NQ + k] * Wenc[t*NQ + k];
        embS[t] = s / (1.0f + __expf(-s));
    }
    if (t >= 64 && t < 64 + DEPTH*NQ) {
        const int gi = t - 64;
        const int d = gi / NQ, ww = gi % NQ;
        const float p0 = wts[(d*NQ + ww)*3 + 0];
        const float p1 = wts[(d*NQ + ww)*3 + 1];
        const float p2 = wts[(d*NQ + ww)*3 + 2];
        float s0, c0, s1, c1, s2, c2;
        sincosf(0.5f*p0, &s0, &c0);
        sincosf(0.5f*p1, &s1, &c1);
        sincosf(0.5f*p2, &s2, &c2);
        // U = RY(p2) * RX(p1) * RZ(p0)
        f2 e0  = (f2){c0, -s0};
        f2 e0c = (f2){c0,  s0};
        f2 is1 = (f2){0.f, -s1};
        f2 m00 = c1 * e0;
        f2 m01 = cmul(is1, e0c);
        f2 m10 = cmul(is1, e0);
        f2 m11 = c1 * e0c;
        f2 u00 = c2*m00 - s2*m10;
        f2 u01 = c2*m01 - s2*m11;
        f2 u10 = s2*m00 + c2*m10;
        f2 u11 = s2*m01 + c2*m11;
        gates[d][ww][0] = (f4){u00.x, u00.y, -u00.y, u00.x};
        gates[d][ww][1] = (f4){u01.x, u01.y, -u01.y, u01.x};
        gates[d][ww][2] = (f4){u10.x, u10.y, -u10.y, u10.x};
        gates[d][ww][3] = (f4){u11.x, u11.y, -u11.y, u11.x};
    }
    __syncthreads();

    // ---- stage 2: per-wire 2-vectors after encoding + layer 0 ----
    if (t < NQ) {
        float v = embS[t];
        float s, c;
        sincosf(0.5f*v, &s, &c);
        f2 a0 = (f2){c*c,  s*s};
        f2 a1 = (f2){s*c, -s*c};
        f2 u00 = gates[0][t][0].xy, u01 = gates[0][t][1].xy;
        f2 u10 = gates[0][t][2].xy, u11 = gates[0][t][3].xy;
        qv[t][0] = cmul(u00, a0) + cmul(u01, a1);
        qv[t][1] = cmul(u10, a0) + cmul(u11, a1);
    }
    __syncthreads();

    // ---- stage 3: partial-product tables ----
    if (t < 128) {
        f2 p = qv[0][(t >> 6) & 1];
        #pragma unroll
        for (int ww = 1; ww <= 6; ++ww) p = cmul(p, qv[ww][(t >> (6 - ww)) & 1]);
        Phi[t] = p;
    } else if (t < 256) {
        const int j = t - 128;
        f2 p = qv[7][(j >> 6) & 1];
        #pragma unroll
        for (int ww = 8; ww <= 13; ++ww) p = cmul(p, qv[ww][(j >> (13 - ww)) & 1]);
        Plo[j] = p;
    }
    __syncthreads();

    // ---- stage 4: build product state IN REGISTERS (M0 view), CZ0 fused ----
    // e = (l<<10)|(n<<4)|w:  Phi idx = e>>7 = (l<<3)|(n>>3);  Plo idx = e&127
    // = ((n&7)<<4)|w  (l-independent -> single read).
    f2 a[16];
    {
        f2 plo = Plo[((n & 7) << 4) | w];
        #pragma unroll
        for (int l = 0; l < 16; ++l)
            a[l] = cmul(Phi[(l << 3) | (n >> 3)], plo);
        cz_M0(a, t);
    }

    // ---- layer 1, part A (M0): q0-3 reg, q4-9 lane ----
    {
        const f4 (*gl)[4] = gates[1];
        reg_gate<8>(a, gl[0]);       // q0 <-> l3
        reg_gate<4>(a, gl[1]);       // q1 <-> l2
        reg_gate<2>(a, gl[2]);       // q2 <-> l1
        reg_gate<1>(a, gl[3]);       // q3 <-> l0
        lane_gate<32>(a, gl[4], t);  // q4 <-> n5
        lane_gate<16>(a, gl[5], t);  // q5 <-> n4
        lane_gate<8>(a, gl[6], t);   // q6 <-> n3
        lane_gate<4>(a, gl[7], t);   // q7 <-> n2
        lane_gate<2>(a, gl[8], t);   // q8 <-> n1
        lane_gate<1>(a, gl[9], t);   // q9 <-> n0
    }

    // ---- remap 1: M0 -> M1 ----
    #pragma unroll
    for (int l = 0; l < 16; ++l) st[t + (l << 10)] = a[l];
    __syncthreads();
    #pragma unroll
    for (int l = 0; l < 16; ++l) a[l] = st[bM1 + (l << 6)];

    // ---- layer 1 part B + CZ1 + layer 2 part A (M1) ----
    {
        const f4 (*gl1)[4] = gates[1];
        reg_gate<8>(a, gl1[10]);     // q10 <-> l3
        reg_gate<4>(a, gl1[11]);     // q11 <-> l2
        reg_gate<2>(a, gl1[12]);     // q12 <-> l1
        reg_gate<1>(a, gl1[13]);     // q13 <-> l0
        cz_M1(a, t);
        const f4 (*gl2)[4] = gates[2];
        lane_gate<32>(a, gl2[4], t);
        lane_gate<16>(a, gl2[5], t);
        lane_gate<8>(a, gl2[6], t);
        lane_gate<4>(a, gl2[7], t);
        lane_gate<2>(a, gl2[8], t);
        lane_gate<1>(a, gl2[9], t);
        reg_gate<8>(a, gl2[10]);
        reg_gate<4>(a, gl2[11]);
        reg_gate<2>(a, gl2[12]);
        reg_gate<1>(a, gl2[13]);
    }

    // ---- remap 2: M1 -> M0 ----
    __syncthreads();   // all waves done reading remap 1
    #pragma unroll
    for (int l = 0; l < 16; ++l) st[bM1 + (l << 6)] = a[l];
    __syncthreads();
    #pragma unroll
    for (int l = 0; l < 16; ++l) a[l] = st[t + (l << 10)];

    // ---- layer 2 part B + CZ2 + layer 3 part A (M0) ----
    {
        const f4 (*gl2)[4] = gates[2];
        reg_gate<8>(a, gl2[0]);
        reg_gate<4>(a, gl2[1]);
        reg_gate<2>(a, gl2[2]);
        reg_gate<1>(a, gl2[3]);
        cz_M0(a, t);
        const f4 (*gl3)[4] = gates[3];
        reg_gate<8>(a, gl3[0]);
        reg_gate<4>(a, gl3[1]);
        reg_gate<2>(a, gl3[2]);
        reg_gate<1>(a, gl3[3]);
        lane_gate<32>(a, gl3[4], t);
        lane_gate<16>(a, gl3[5], t);
        lane_gate<8>(a, gl3[6], t);
        lane_gate<4>(a, gl3[7], t);
        lane_gate<2>(a, gl3[8], t);
        lane_gate<1>(a, gl3[9], t);
    }

    // ---- remap 3: M0 -> M1 ----
    __syncthreads();
    #pragma unroll
    for (int l = 0; l < 16; ++l) st[t + (l << 10)] = a[l];
    __syncthreads();
    #pragma unroll
    for (int l = 0; l < 16; ++l) a[l] = st[bM1 + (l << 6)];

    // ---- layer 3 part B (M1) + fused probability reduction ----
    float SU, Q10, Q11, Q12, Q13;
    {
        const f4 (*gl3)[4] = gates[3];
        reg_gate<8>(a, gl3[10]);
        reg_gate<4>(a, gl3[11]);
        reg_gate<2>(a, gl3[12]);
        reg_gate<1>(a, gl3[13]);
        // (CZ after layer 3 dropped: |psi|^2 invariant)
        SU = Q10 = Q11 = Q12 = Q13 = 0.f;
        #pragma unroll
        for (int l = 0; l < 16; ++l) {
            float p = a[l].x*a[l].x + a[l].y*a[l].y;
            SU  += p;
            Q10 += (l & 8) ? -p : p;    // q10 <-> e3 = l3
            Q11 += (l & 4) ? -p : p;
            Q12 += (l & 2) ? -p : p;
            Q13 += (l & 1) ? -p : p;
        }
    }

    // ---- stage 6: reduce to 14 expectations, layernorm ----
    // In M1, wire w's sign bit e[13-w]: q0-3 <-> w-bits t[9:6], q4-9 <-> n-bits
    // t[5:0] -> sign = (t >> (9-w)) & 1 for w = 0..9, all thread-uniform.
    {
        const int lane = t & 63, wv = t >> 6;
        #pragma unroll
        for (int ww = 0; ww < NQ; ++ww) {
            float v;
            if      (ww == 10) v = Q10;
            else if (ww == 11) v = Q11;
            else if (ww == 12) v = Q12;
            else if (ww == 13) v = Q13;
            else               v = ((t >> (9 - ww)) & 1) ? -SU : SU;
            #pragma unroll
            for (int off = 32; off > 0; off >>= 1) v += __shfl_down(v, off, 64);
            if (lane == 0) wred[wv][ww] = v;
        }
    }
    __syncthreads();
    if (t < NQ) {
        float s = 0.f;
        #pragma unroll
        for (int k = 0; k < 16; ++k) s += wred[k][t];
        lat[t] = s;
    }
    __syncthreads();
    if (t < NQ) {
        float mu = 0.f;
        #pragma unroll
        for (int k = 0; k < NQ; ++k) mu += lat[k];
        mu *= (1.0f / NQ);
        float var = 0.f;
        #pragma unroll
        for (int k = 0; k < NQ; ++k) { float dv = lat[k] - mu; var += dv*dv; }
        var *= (1.0f / NQ);
        out[b*NQ + t] = (lat[t] - mu) * rsqrtf(var + 1e-5f);
    }
}

extern "C" void kernel_launch(void* const* d_in, const int* in_sizes, int n_in,
                              void* d_out, int out_size, void* d_ws, size_t ws_size,
                              hipStream_t stream)
{
    (void)n_in; (void)d_ws; (void)ws_size; (void)out_size;
    const float* cond = (const float*)d_in[0];
    const float* Wenc = (const float*)d_in[1];
    const float* benc = (const float*)d_in[2];
    const float* wts  = (const float*)d_in[3];
    float* out = (float*)d_out;
    const int B = in_sizes[0] / NQ;   // 256
    qlg_kernel<<<dim3(B), dim3(1024), 0, stream>>>(cond, Wenc, benc, wts, out);
}

// Round 10
// 95.146 us; speedup vs baseline: 1.0900x; 1.0069x over previous
//
#include <hip/hip_runtime.h>
#include <math.h>

#define NQ    14
#define DIM   16384
#define DEPTH 4

// Packed-fp32 complex: f2 = (re, im) -> v_pk_fma_f32.
typedef __attribute__((ext_vector_type(2))) float f2;
typedef __attribute__((ext_vector_type(4))) float f4;

__device__ __forceinline__ f2 cmul(f2 a, f2 b) {
    return (f2){a.x*b.x - a.y*b.y, a.x*b.y + a.y*b.x};
}
// out = u*x + v*y (complex), pre-swapped forms us=(-u.i,u.r): 1 pk_mul + 3 pk_fma
__device__ __forceinline__ f2 cmac2(f2 x, f2 u, f2 us, f2 y, f2 v, f2 vs) {
    f2 r = x.xx * u;
    r += x.yy * us;
    r += y.xx * v;
    r += y.yy * vs;
    return r;
}

// ---------------- register-resident state, two views ----------------
// 1024 threads x 16 amps = the full state in registers. n = t&63, w = t>>6.
// Qubit q <-> amplitude bit e[13-q].
// View A: e13..e10 = l3..l0 (q0-3 reg); e9..e4 = n5..n0 (q4-9 lane);
//         e3..e0 = w3..w0 (q10-13 wave).
//   A-cheap gates: q0-3 (reg), q6 (n3, DPP xor8), q8 (n1, DPP xor2),
//   q9 (n0, DPP xor1).  q4,q5,q7 are NEVER gated in A (LDS-pipe xors).
// View B: e3..e0 = l3..l0 (q10-13 reg); e13..e10 = w3..w0 (q0-3 wave);
//         e9=n3, e8=n1, e7=n5, e6=n0, e5=n4, e4=n2.
//   B-cheap gates: q10-13 (reg), q4 (n3, xor8), q5 (n1, xor2), q7 (n0, xor1).
// A-cheap ∪ B-cheap covers all 14 qubits; every lane gate is DPP — zero
// ds_swizzle/shfl in the whole circuit (round 9's remaining lgkm stalls).
//
// Remap LDS layout: L(e) = e[7:4] | (e[9:8]<<4) | (e[3:0]<<6) | (e[13:10]<<10)
//   A-side address: t + (l<<10)      (bank pair L[3:0] = n[3:0]: 16x4 lanes)
//   B-side address: baseB(n,w) + (l<<6), baseB = (w<<10)|(n3<<5)|(n1<<4)|
//                   (n5<<3)|(n0<<2)|(n4<<1)|n2   (bank pair = n5,n0,n4,n2)
// Both sides base + compile-const*l -> pure imm offsets.

// ---- cross-lane exchanges (all DPP = pure VALU) ----
template<int CTRL>
__device__ __forceinline__ f2 dpp2(f2 v) {
    union U { f2 f; int i[2]; } u, r;
    u.f = v;
    r.i[0] = __builtin_amdgcn_update_dpp(0, u.i[0], CTRL, 0xF, 0xF, true);
    r.i[1] = __builtin_amdgcn_update_dpp(0, u.i[1], CTRL, 0xF, 0xF, true);
    return r.f;
}
template<int XB> __device__ __forceinline__ f2 lxchg(f2 v);
template<> __device__ __forceinline__ f2 lxchg<1>(f2 v) { return dpp2<0xB1>(v); }   // quad_perm [1,0,3,2]
template<> __device__ __forceinline__ f2 lxchg<2>(f2 v) { return dpp2<0x4E>(v); }   // quad_perm [2,3,0,1]
template<> __device__ __forceinline__ f2 lxchg<8>(f2 v) { return dpp2<0x128>(v); }  // row_ror:8 == xor8

// Register-qubit gate over 16 amps: butterfly across amp-index bit MASK.
template<int MASK>
__device__ __forceinline__ void reg_gate(f2 a[16], const f4* G) {
    f4 g0 = G[0], g1 = G[1], g2 = G[2], g3 = G[3];
    #pragma unroll
    for (int l = 0; l < 16; ++l) {
        if (l & MASK) continue;
        const int j = l | MASK;
        f2 x = a[l], y = a[j];
        a[l] = cmac2(x, g0.xy, g0.zw, y, g1.xy, g1.zw);
        a[j] = cmac2(x, g2.xy, g2.zw, y, g3.xy, g3.zw);
    }
}

// Lane-qubit gate: DPP exchange; each lane computes its own half.
// lo lane: rows 0,1 = (u00,u01); hi lane: rows 3,2 = (u11,u10).
template<int XB>
__device__ __forceinline__ void lane_gate(f2 a[16], const f4* G, int t) {
    const bool hi = (t & XB) != 0;
    f4 c1 = G[hi ? 3 : 0];
    f4 c2 = G[hi ? 2 : 1];
    #pragma unroll
    for (int l = 0; l < 16; ++l) {
        f2 p = lxchg<XB>(a[l]);
        a[l] = cmac2(a[l], c1.xy, c1.zw, p, c2.xy, c2.zw);
    }
}

// CZ sign in view A: e = (l<<10)|(n<<4)|w.
// parity = [pairs in w] ^ (n0&w3) ^ [pairs in n] ^ (l0&n5) ^ [pairs in l].
__device__ __forceinline__ void cz_A(f2 a[16], int t) {
    const int n = t & 63, w = t >> 6;
    const int pT = (__popc(w & (w >> 1)) + __popc(n & (n >> 1)) + ((n & 1) & (w >> 3))) & 1;
    const float F0 = pT ? -1.f : 1.f;
    const float F1 = (pT ^ ((n >> 5) & 1)) ? -1.f : 1.f;
    #pragma unroll
    for (int l = 0; l < 16; ++l) {
        float s = (l & 1) ? F1 : F0;                 // cross term l0 & n5
        if (__popc(l & (l >> 1)) & 1) s = -s;        // compile-time per l
        a[l] *= s;
    }
}

// CZ sign in view B: e9=n3,e8=n1,e7=n5,e6=n0,e5=n4,e4=n2, e13..10=w, e3..0=l.
// parity = (n2&n4)^(n4&n0)^(n0&n5)^(n5&n1)^(n1&n3)^(n3&w0)^[pairs in w]
//          ^ (l3&n2 cross) ^ [pairs in l].
__device__ __forceinline__ void cz_B(f2 a[16], int t) {
    const int n = t & 63, w = t >> 6;
    const int n0 = n & 1, n1 = (n >> 1) & 1, n2 = (n >> 2) & 1;
    const int n3 = (n >> 3) & 1, n4 = (n >> 4) & 1, n5 = (n >> 5) & 1;
    const int pT = ((n2 & n4) ^ (n4 & n0) ^ (n0 & n5) ^ (n5 & n1) ^ (n1 & n3)
                    ^ (n3 & (w & 1)) ^ (__popc(w & (w >> 1)) & 1));
    const float F0 = pT ? -1.f : 1.f;
    const float F1 = (pT ^ n2) ? -1.f : 1.f;
    #pragma unroll
    for (int l = 0; l < 16; ++l) {
        float s = (l & 8) ? F1 : F0;                 // cross term l3 & n2
        if (__popc(l & (l >> 1)) & 1) s = -s;        // compile-time per l
        a[l] *= s;
    }
}

__global__ __launch_bounds__(1024)
void qlg_kernel(const float* __restrict__ cond,
                const float* __restrict__ Wenc,
                const float* __restrict__ benc,
                const float* __restrict__ wts,
                float* __restrict__ out)
{
    __shared__ f2 st[DIM];                  // 128 KB remap buffer (L-layout)
    __shared__ f4 gates[DEPTH][NQ][4];      // per gate row: (u | u_swapped)
    __shared__ f2 qv[NQ][2];
    __shared__ f2 Phi[128];
    __shared__ f2 Plo[128];
    __shared__ float embS[NQ];
    __shared__ float wred[16][NQ];
    __shared__ float lat[NQ];

    const int b = blockIdx.x;
    const int t = threadIdx.x;
    const int n = t & 63, w = t >> 6;
    // B-side remap base: (w<<10)|(n3<<5)|(n1<<4)|(n5<<3)|(n0<<2)|(n4<<1)|n2
    const int bB = (w << 10)
                 | (((n >> 3) & 1) << 5) | (((n >> 1) & 1) << 4)
                 | (((n >> 5) & 1) << 3) | ((n & 1) << 2)
                 | (((n >> 4) & 1) << 1) | ((n >> 2) & 1);

    // ---- stage 1: embedding (SiLU) + gate matrices ----
    if (t < NQ) {
        float s = benc[t];
        #pragma unroll
        for (int k = 0; k < NQ; ++k) s += cond[b*NQ + k] * Wenc[t*NQ + k];
        embS[t] = s / (1.0f + __expf(-s));
    }
    if (t >= 64 && t < 64 + DEPTH*NQ) {
        const int gi = t - 64;
        const int d = gi / NQ, ww = gi % NQ;
        const float p0 = wts[(d*NQ + ww)*3 + 0];
        const float p1 = wts[(d*NQ + ww)*3 + 1];
        const float p2 = wts[(d*NQ + ww)*3 + 2];
        float s0, c0, s1, c1, s2, c2;
        sincosf(0.5f*p0, &s0, &c0);
        sincosf(0.5f*p1, &s1, &c1);
        sincosf(0.5f*p2, &s2, &c2);
        // U = RY(p2) * RX(p1) * RZ(p0)
        f2 e0  = (f2){c0, -s0};
        f2 e0c = (f2){c0,  s0};
        f2 is1 = (f2){0.f, -s1};
        f2 m00 = c1 * e0;
        f2 m01 = cmul(is1, e0c);
        f2 m10 = cmul(is1, e0);
        f2 m11 = c1 * e0c;
        f2 u00 = c2*m00 - s2*m10;
        f2 u01 = c2*m01 - s2*m11;
        f2 u10 = s2*m00 + c2*m10;
        f2 u11 = s2*m01 + c2*m11;
        gates[d][ww][0] = (f4){u00.x, u00.y, -u00.y, u00.x};
        gates[d][ww][1] = (f4){u01.x, u01.y, -u01.y, u01.x};
        gates[d][ww][2] = (f4){u10.x, u10.y, -u10.y, u10.x};
        gates[d][ww][3] = (f4){u11.x, u11.y, -u11.y, u11.x};
    }
    __syncthreads();

    // ---- stage 2: per-wire 2-vectors after encoding + layer 0 ----
    if (t < NQ) {
        float v = embS[t];
        float s, c;
        sincosf(0.5f*v, &s, &c);
        f2 a0 = (f2){c*c,  s*s};
        f2 a1 = (f2){s*c, -s*c};
        f2 u00 = gates[0][t][0].xy, u01 = gates[0][t][1].xy;
        f2 u10 = gates[0][t][2].xy, u11 = gates[0][t][3].xy;
        qv[t][0] = cmul(u00, a0) + cmul(u01, a1);
        qv[t][1] = cmul(u10, a0) + cmul(u11, a1);
    }
    __syncthreads();

    // ---- stage 3: partial-product tables ----
    if (t < 128) {
        f2 p = qv[0][(t >> 6) & 1];
        #pragma unroll
        for (int ww = 1; ww <= 6; ++ww) p = cmul(p, qv[ww][(t >> (6 - ww)) & 1]);
        Phi[t] = p;
    } else if (t < 256) {
        const int j = t - 128;
        f2 p = qv[7][(j >> 6) & 1];
        #pragma unroll
        for (int ww = 8; ww <= 13; ++ww) p = cmul(p, qv[ww][(j >> (13 - ww)) & 1]);
        Plo[j] = p;
    }
    __syncthreads();

    // ---- stage 4: build product state IN REGISTERS (view A), CZ0 fused ----
    // e = (l<<10)|(n<<4)|w: Phi idx = (l<<3)|(n>>3); Plo idx = ((n&7)<<4)|w.
    f2 a[16];
    {
        f2 plo = Plo[((n & 7) << 4) | w];
        #pragma unroll
        for (int l = 0; l < 16; ++l)
            a[l] = cmul(Phi[(l << 3) | (n >> 3)], plo);
        cz_A(a, t);
    }

    // ---- layer 1, A-part: q0-3 reg, q6/q8/q9 DPP ----
    {
        const f4 (*gl)[4] = gates[1];
        reg_gate<8>(a, gl[0]);       // q0 <-> l3
        reg_gate<4>(a, gl[1]);       // q1 <-> l2
        reg_gate<2>(a, gl[2]);       // q2 <-> l1
        reg_gate<1>(a, gl[3]);       // q3 <-> l0
        lane_gate<8>(a, gl[6], t);   // q6 <-> n3
        lane_gate<2>(a, gl[8], t);   // q8 <-> n1
        lane_gate<1>(a, gl[9], t);   // q9 <-> n0
    }

    // ---- remap 1: A -> B ----
    #pragma unroll
    for (int l = 0; l < 16; ++l) st[t + (l << 10)] = a[l];
    __syncthreads();
    #pragma unroll
    for (int l = 0; l < 16; ++l) a[l] = st[bB + (l << 6)];

    // ---- layer 1 B-part + CZ1 + layer 2 B-part (view B) ----
    {
        const f4 (*gl1)[4] = gates[1];
        reg_gate<8>(a, gl1[10]);     // q10 <-> l3
        reg_gate<4>(a, gl1[11]);     // q11 <-> l2
        reg_gate<2>(a, gl1[12]);     // q12 <-> l1
        reg_gate<1>(a, gl1[13]);     // q13 <-> l0
        lane_gate<8>(a, gl1[4], t);  // q4 <-> n3
        lane_gate<2>(a, gl1[5], t);  // q5 <-> n1
        lane_gate<1>(a, gl1[7], t);  // q7 <-> n0
        cz_B(a, t);
        const f4 (*gl2)[4] = gates[2];
        reg_gate<8>(a, gl2[10]);
        reg_gate<4>(a, gl2[11]);
        reg_gate<2>(a, gl2[12]);
        reg_gate<1>(a, gl2[13]);
        lane_gate<8>(a, gl2[4], t);
        lane_gate<2>(a, gl2[5], t);
        lane_gate<1>(a, gl2[7], t);
    }

    // ---- remap 2: B -> A ----
    __syncthreads();   // all waves done reading remap 1
    #pragma unroll
    for (int l = 0; l < 16; ++l) st[bB + (l << 6)] = a[l];
    __syncthreads();
    #pragma unroll
    for (int l = 0; l < 16; ++l) a[l] = st[t + (l << 10)];

    // ---- layer 2 A-part + CZ2 + layer 3 A-part (view A) ----
    {
        const f4 (*gl2)[4] = gates[2];
        reg_gate<8>(a, gl2[0]);
        reg_gate<4>(a, gl2[1]);
        reg_gate<2>(a, gl2[2]);
        reg_gate<1>(a, gl2[3]);
        lane_gate<8>(a, gl2[6], t);
        lane_gate<2>(a, gl2[8], t);
        lane_gate<1>(a, gl2[9], t);
        cz_A(a, t);
        const f4 (*gl3)[4] = gates[3];
        reg_gate<8>(a, gl3[0]);
        reg_gate<4>(a, gl3[1]);
        reg_gate<2>(a, gl3[2]);
        reg_gate<1>(a, gl3[3]);
        lane_gate<8>(a, gl3[6], t);
        lane_gate<2>(a, gl3[8], t);
        lane_gate<1>(a, gl3[9], t);
    }

    // ---- remap 3: A -> B ----
    __syncthreads();
    #pragma unroll
    for (int l = 0; l < 16; ++l) st[t + (l << 10)] = a[l];
    __syncthreads();
    #pragma unroll
    for (int l = 0; l < 16; ++l) a[l] = st[bB + (l << 6)];

    // ---- layer 3 B-part (view B) + fused probability reduction ----
    float SU, Q10, Q11, Q12, Q13;
    {
        const f4 (*gl3)[4] = gates[3];
        reg_gate<8>(a, gl3[10]);
        reg_gate<4>(a, gl3[11]);
        reg_gate<2>(a, gl3[12]);
        reg_gate<1>(a, gl3[13]);
        lane_gate<8>(a, gl3[4], t);
        lane_gate<2>(a, gl3[5], t);
        lane_gate<1>(a, gl3[7], t);
        // (CZ after layer 3 dropped: |psi|^2 invariant)
        SU = Q10 = Q11 = Q12 = Q13 = 0.f;
        #pragma unroll
        for (int l = 0; l < 16; ++l) {
            float p = a[l].x*a[l].x + a[l].y*a[l].y;
            SU  += p;
            Q10 += (l & 8) ? -p : p;    // q10 <-> e3 = l3
            Q11 += (l & 4) ? -p : p;
            Q12 += (l & 2) ? -p : p;
            Q13 += (l & 1) ? -p : p;
        }
    }

    // ---- stage 6: reduce to 14 expectations, layernorm ----
    // View-B sign bit (thread-uniform) for wire ww in 0..9:
    // q0:t9 q1:t8 q2:t7 q3:t6 q4:t3 q5:t1 q6:t5 q7:t0 q8:t4 q9:t2.
    {
        const int lane = t & 63, wv = t >> 6;
        const int sbit[10] = {9, 8, 7, 6, 3, 1, 5, 0, 4, 2};
        #pragma unroll
        for (int ww = 0; ww < NQ; ++ww) {
            float v;
            if      (ww == 10) v = Q10;
            else if (ww == 11) v = Q11;
            else if (ww == 12) v = Q12;
            else if (ww == 13) v = Q13;
            else               v = ((t >> sbit[ww]) & 1) ? -SU : SU;
            #pragma unroll
            for (int off = 32; off > 0; off >>= 1) v += __shfl_down(v, off, 64);
            if (lane == 0) wred[wv][ww] = v;
        }
    }
    __syncthreads();
    if (t < NQ) {
        float s = 0.f;
        #pragma unroll
        for (int k = 0; k < 16; ++k) s += wred[k][t];
        lat[t] = s;
    }
    __syncthreads();
    if (t < NQ) {
        float mu = 0.f;
        #pragma unroll
        for (int k = 0; k < NQ; ++k) mu += lat[k];
        mu *= (1.0f / NQ);
        float var = 0.f;
        #pragma unroll
        for (int k = 0; k < NQ; ++k) { float dv = lat[k] - mu; var += dv*dv; }
        var *= (1.0f / NQ);
        out[b*NQ + t] = (lat[t] - mu) * rsqrtf(var + 1e-5f);
    }
}

extern "C" void kernel_launch(void* const* d_in, const int* in_sizes, int n_in,
                              void* d_out, int out_size, void* d_ws, size_t ws_size,
                              hipStream_t stream)
{
    (void)n_in; (void)d_ws; (void)ws_size; (void)out_size;
    const float* cond = (const float*)d_in[0];
    const float* Wenc = (const float*)d_in[1];
    const float* benc = (const float*)d_in[2];
    const float* wts  = (const float*)d_in[3];
    float* out = (float*)d_out;
    const int B = in_sizes[0] / NQ;   // 256
    qlg_kernel<<<dim3(B), dim3(1024), 0, stream>>>(cond, Wenc, benc, wts, out);
}